// Round 1
// baseline (705.649 us; speedup 1.0000x reference)
//
#include <hip/hip_runtime.h>

#define N_NODES 100000
#define N_EDGES 1600000
#define IN_F 128
#define HID 64
#define NCLS 2

// ---------- degree / normalization ----------
__global__ __launch_bounds__(256) void k_deg_init(float* __restrict__ deg) {
    int i = blockIdx.x * 256 + threadIdx.x;
    if (i < N_NODES) deg[i] = 1.0f;   // self-loop contributes 1
}

__global__ __launch_bounds__(256) void k_deg_count(const int* __restrict__ dst,
                                                   float* __restrict__ deg) {
    int e = blockIdx.x * 256 + threadIdx.x;
    if (e < N_EDGES) atomicAdd(&deg[dst[e]], 1.0f);
}

__global__ __launch_bounds__(256) void k_dinv(float* __restrict__ deg) {
    int i = blockIdx.x * 256 + threadIdx.x;
    if (i < N_NODES) deg[i] = rsqrtf(deg[i]);   // deg >= 1, in-place -> dinv
}

// ---------- layer 1 GEMM: h' = (x @ W1) * dinv ; acc initialized to h' (self-loop) ----------
__global__ __launch_bounds__(256) void k_gemm1(const float* __restrict__ x,
                                               const float* __restrict__ W1,
                                               const float* __restrict__ dinv,
                                               float* __restrict__ h,
                                               float* __restrict__ acc) {
    __shared__ float Ws[IN_F * HID];   // 32 KB, loaded once per block
    __shared__ float xs[4][IN_F];      // 2 KB, 4 node rows per group
    for (int t = threadIdx.x; t < IN_F * HID; t += 256) Ws[t] = W1[t];
    const int s = threadIdx.x >> 6;    // sub-node 0..3
    const int j = threadIdx.x & 63;    // output feature
    const int ngroups = N_NODES / 4;   // 25000, exact
    for (int g = blockIdx.x; g < ngroups; g += gridDim.x) {
        __syncthreads();               // also covers Ws load on first iter
        for (int t = threadIdx.x; t < 4 * IN_F; t += 256)
            xs[t >> 7][t & 127] = x[(g * 4 + (t >> 7)) * IN_F + (t & 127)];
        __syncthreads();
        const int node = g * 4 + s;
        float sum = 0.f;
        #pragma unroll
        for (int k = 0; k < IN_F; ++k) sum += xs[s][k] * Ws[k * HID + j];
        const float hv = sum * dinv[node];
        h[node * HID + j]   = hv;
        acc[node * HID + j] = hv;      // self-loop term pre-seeded
    }
}

// ---------- layer 1 scatter: acc[dst] += h'[src] ----------
__global__ __launch_bounds__(256) void k_scatter1(const int* __restrict__ src,
                                                  const int* __restrict__ dst,
                                                  const float* __restrict__ h,
                                                  float* __restrict__ acc) {
    int gid = blockIdx.x * 256 + threadIdx.x;   // max 102.4M, fits int
    int e = gid >> 6;
    if (e >= N_EDGES) return;
    int f = gid & 63;
    int sn = src[e], dn = dst[e];
    atomicAdd(&acc[dn * HID + f], h[sn * HID + f]);
}

// ---------- layer 1 finalize: y = relu(dinv*acc + b1) ----------
__global__ __launch_bounds__(256) void k_fin1(const float* __restrict__ acc,
                                              const float* __restrict__ dinv,
                                              const float* __restrict__ b1,
                                              float* __restrict__ y) {
    int gid = blockIdx.x * 256 + threadIdx.x;
    if (gid >= N_NODES * HID) return;
    int i = gid >> 6, j = gid & 63;
    float v = dinv[i] * acc[gid] + b1[j];
    y[gid] = v > 0.f ? v : 0.f;
}

// ---------- layer 2 GEMM: h2' = (y @ W2) * dinv ; out seeded with h2' (self-loop) ----------
__global__ __launch_bounds__(256) void k_gemm2(const float* __restrict__ y,
                                               const float* __restrict__ W2,
                                               const float* __restrict__ dinv,
                                               float* __restrict__ h2,
                                               float* __restrict__ out) {
    __shared__ float Ws[HID * NCLS];   // 512 B
    if (threadIdx.x < HID * NCLS) Ws[threadIdx.x] = W2[threadIdx.x];
    __syncthreads();
    int i = blockIdx.x * 256 + threadIdx.x;
    if (i >= N_NODES) return;
    const float4* yr = (const float4*)(y + (size_t)i * HID);
    float c0 = 0.f, c1 = 0.f;
    #pragma unroll
    for (int q = 0; q < HID / 4; ++q) {
        float4 v = yr[q];
        c0 += v.x * Ws[(q*4+0)*2+0] + v.y * Ws[(q*4+1)*2+0]
            + v.z * Ws[(q*4+2)*2+0] + v.w * Ws[(q*4+3)*2+0];
        c1 += v.x * Ws[(q*4+0)*2+1] + v.y * Ws[(q*4+1)*2+1]
            + v.z * Ws[(q*4+2)*2+1] + v.w * Ws[(q*4+3)*2+1];
    }
    const float di = dinv[i];
    c0 *= di; c1 *= di;
    h2[i*2+0] = c0; h2[i*2+1] = c1;
    out[i*2+0] = c0; out[i*2+1] = c1;   // self-loop seed (also fully initializes d_out)
}

// ---------- layer 2 scatter ----------
__global__ __launch_bounds__(256) void k_scatter2(const int* __restrict__ src,
                                                  const int* __restrict__ dst,
                                                  const float* __restrict__ h2,
                                                  float* __restrict__ out) {
    int gid = blockIdx.x * 256 + threadIdx.x;
    if (gid >= N_EDGES * 2) return;
    int e = gid >> 1, c = gid & 1;
    atomicAdd(&out[dst[e] * 2 + c], h2[src[e] * 2 + c]);
}

// ---------- layer 2 finalize: out = dinv*out + b2 ----------
__global__ __launch_bounds__(256) void k_fin2(float* __restrict__ out,
                                              const float* __restrict__ dinv,
                                              const float* __restrict__ b2) {
    int gid = blockIdx.x * 256 + threadIdx.x;
    if (gid >= N_NODES * 2) return;
    int i = gid >> 1, c = gid & 1;
    out[gid] = dinv[i] * out[gid] + b2[c];
}

extern "C" void kernel_launch(void* const* d_in, const int* in_sizes, int n_in,
                              void* d_out, int out_size, void* d_ws, size_t ws_size,
                              hipStream_t stream) {
    const float* x  = (const float*)d_in[0];
    const int*   ei = (const int*)d_in[1];   // [2, E] int32 (harness converts integer inputs)
    const float* W1 = (const float*)d_in[2];
    const float* b1 = (const float*)d_in[3];
    const float* W2 = (const float*)d_in[4];
    const float* b2 = (const float*)d_in[5];
    float* out = (float*)d_out;

    const int* src = ei;
    const int* dst = ei + N_EDGES;

    // workspace layout (floats): dinv | bufA (h1'/y) | bufB (acc1) | bufC (h2')
    float* wsf  = (float*)d_ws;
    float* dinv = wsf;                               // 100000 (padded to 100352 for 16B align)
    float* bufA = wsf + 100352;                      // 6.4M floats
    float* bufB = bufA + (size_t)N_NODES * HID;      // 6.4M floats
    float* bufC = bufB + (size_t)N_NODES * HID;      // 200000 floats

    dim3 B(256);
    k_deg_init <<<(N_NODES + 255) / 256, B, 0, stream>>>(dinv);
    k_deg_count<<<(N_EDGES + 255) / 256, B, 0, stream>>>(dst, dinv);
    k_dinv     <<<(N_NODES + 255) / 256, B, 0, stream>>>(dinv);

    k_gemm1    <<<1024, B, 0, stream>>>(x, W1, dinv, bufA, bufB);
    k_scatter1 <<<(N_EDGES * 64) / 256, B, 0, stream>>>(src, dst, bufA, bufB);
    k_fin1     <<<(N_NODES * HID + 255) / 256, B, 0, stream>>>(bufB, dinv, b1, bufA);

    k_gemm2    <<<(N_NODES + 255) / 256, B, 0, stream>>>(bufA, W2, dinv, bufC, out);
    k_scatter2 <<<(N_EDGES * 2 + 255) / 256, B, 0, stream>>>(src, dst, bufC, out);
    k_fin2     <<<(N_NODES * 2 + 255) / 256, B, 0, stream>>>(out, dinv, b2);
}

// Round 2
// 457.125 us; speedup vs baseline: 1.5437x; 1.5437x over previous
//
#include <hip/hip_runtime.h>

#define N_NODES 100000
#define N_EDGES 1600000
#define IN_F 128
#define HID 64

// ---------------- CSR construction ----------------
__global__ __launch_bounds__(256) void k_zero_cnt(int* __restrict__ cnt) {
    int i = blockIdx.x * 256 + threadIdx.x;
    if (i < N_NODES) cnt[i] = 0;
}

__global__ __launch_bounds__(256) void k_hist(const int* __restrict__ dst,
                                              int* __restrict__ cnt) {
    int e = blockIdx.x * 256 + threadIdx.x;
    if (e < N_EDGES) atomicAdd(&cnt[dst[e]], 1);
}

__global__ __launch_bounds__(256) void k_dinv(const int* __restrict__ cnt,
                                              float* __restrict__ dinv) {
    int i = blockIdx.x * 256 + threadIdx.x;
    if (i < N_NODES) dinv[i] = rsqrtf((float)(cnt[i] + 1));  // +1 self-loop
}

// per-block inclusive scan of cnt -> loc, block sums -> bsum
__global__ __launch_bounds__(256) void k_scan_block(const int* __restrict__ cnt,
                                                    int* __restrict__ loc,
                                                    int* __restrict__ bsum) {
    __shared__ int s[256];
    int i = blockIdx.x * 256 + threadIdx.x;
    int v = (i < N_NODES) ? cnt[i] : 0;
    s[threadIdx.x] = v;
    __syncthreads();
    for (int o = 1; o < 256; o <<= 1) {
        int t = (threadIdx.x >= o) ? s[threadIdx.x - o] : 0;
        __syncthreads();
        s[threadIdx.x] += t;
        __syncthreads();
    }
    if (i < N_NODES) loc[i] = s[threadIdx.x];
    if (threadIdx.x == 255) bsum[blockIdx.x] = s[255];
}

// single-block exclusive scan of 391 block sums -> boff
__global__ __launch_bounds__(512) void k_scan_top(const int* __restrict__ bsum,
                                                  int* __restrict__ boff, int nb) {
    __shared__ int s[512];
    int v = (threadIdx.x < nb) ? bsum[threadIdx.x] : 0;
    s[threadIdx.x] = v;
    __syncthreads();
    for (int o = 1; o < 512; o <<= 1) {
        int t = (threadIdx.x >= o) ? s[threadIdx.x - o] : 0;
        __syncthreads();
        s[threadIdx.x] += t;
        __syncthreads();
    }
    if (threadIdx.x < nb) boff[threadIdx.x] = s[threadIdx.x] - v;
}

__global__ __launch_bounds__(256) void k_scan_fin(const int* __restrict__ cnt,
                                                  const int* __restrict__ loc,
                                                  const int* __restrict__ boff,
                                                  int* __restrict__ off,
                                                  int* __restrict__ cursor) {
    int i = blockIdx.x * 256 + threadIdx.x;
    if (i < N_NODES) {
        int o = loc[i] - cnt[i] + boff[blockIdx.x];  // exclusive global
        off[i] = o;
        cursor[i] = o;
    }
    if (i == 0) off[N_NODES] = N_EDGES;
}

__global__ __launch_bounds__(256) void k_reorder(const int* __restrict__ src,
                                                 const int* __restrict__ dst,
                                                 int* __restrict__ cursor,
                                                 int* __restrict__ csr) {
    int e = blockIdx.x * 256 + threadIdx.x;
    if (e < N_EDGES) {
        int slot = atomicAdd(&cursor[dst[e]], 1);
        csr[slot] = src[e];
    }
}

// ---------------- layer 1 GEMM: h' = (x @ W1) * dinv, 4-node register tile ----------------
__global__ __launch_bounds__(256) void k_gemm1(const float* __restrict__ x,
                                               const float* __restrict__ W1,
                                               const float* __restrict__ dinv,
                                               float* __restrict__ h) {
    __shared__ float Ws[IN_F * HID];   // 32 KB
    __shared__ float xs[16][IN_F];     // 8 KB
    for (int t = threadIdx.x; t < IN_F * HID; t += 256) Ws[t] = W1[t];
    const int wave = threadIdx.x >> 6, lane = threadIdx.x & 63;
    const int ngroups = N_NODES / 16;  // 6250, exact
    for (int g = blockIdx.x; g < ngroups; g += gridDim.x) {
        __syncthreads();               // covers Ws load on first iter
        for (int t = threadIdx.x; t < 16 * IN_F; t += 256)
            xs[t >> 7][t & 127] = x[(size_t)(g * 16 + (t >> 7)) * IN_F + (t & 127)];
        __syncthreads();
        const int n0 = g * 16 + wave * 4;
        float a0 = 0.f, a1 = 0.f, a2 = 0.f, a3 = 0.f;
        #pragma unroll 8
        for (int k = 0; k < IN_F; ++k) {
            float wv = Ws[k * HID + lane];
            a0 += xs[wave * 4 + 0][k] * wv;
            a1 += xs[wave * 4 + 1][k] * wv;
            a2 += xs[wave * 4 + 2][k] * wv;
            a3 += xs[wave * 4 + 3][k] * wv;
        }
        h[(size_t)(n0 + 0) * HID + lane] = a0 * dinv[n0 + 0];
        h[(size_t)(n0 + 1) * HID + lane] = a1 * dinv[n0 + 1];
        h[(size_t)(n0 + 2) * HID + lane] = a2 * dinv[n0 + 2];
        h[(size_t)(n0 + 3) * HID + lane] = a3 * dinv[n0 + 3];
    }
}

// ---------------- layer 1 gather + ReLU + GEMM2 fused ----------------
// wave per node: agg = h'[d] + sum_{e in CSR[d]} h'[src[e]] (lane = feature)
// y = relu(dinv*agg + b1); h2'[d] = dinv[d] * (y @ W2)  via wave reduction
__global__ __launch_bounds__(256) void k_gather1(const float* __restrict__ h1,
                                                 const int* __restrict__ off,
                                                 const int* __restrict__ csr,
                                                 const float* __restrict__ dinv,
                                                 const float* __restrict__ b1,
                                                 const float* __restrict__ W2,
                                                 float2* __restrict__ h2p) {
    const int wave = threadIdx.x >> 6, lane = threadIdx.x & 63;
    const int d = blockIdx.x * 4 + wave;   // grid = 25000 blocks, exact
    const int beg = off[d], end = off[d + 1];
    float acc = h1[(size_t)d * HID + lane];           // self-loop term
    for (int base = beg; base < end; base += 64) {
        const int cnt = min(64, end - base);
        int sidx = (lane < cnt) ? csr[base + lane] : 0;
        for (int j = 0; j < cnt; ++j) {
            int s = __shfl(sidx, j, 64);
            acc += h1[(size_t)s * HID + lane];
        }
    }
    float y = dinv[d] * acc + b1[lane];
    y = y > 0.f ? y : 0.f;
    float c0 = y * W2[lane * 2 + 0];
    float c1 = y * W2[lane * 2 + 1];
    #pragma unroll
    for (int o = 32; o > 0; o >>= 1) {
        c0 += __shfl_xor(c0, o, 64);
        c1 += __shfl_xor(c1, o, 64);
    }
    if (lane == 0) {
        float di = dinv[d];
        h2p[d] = make_float2(c0 * di, c1 * di);
    }
}

// ---------------- layer 2 gather + finalize ----------------
__global__ __launch_bounds__(256) void k_gather2(const float2* __restrict__ h2p,
                                                 const int* __restrict__ off,
                                                 const int* __restrict__ csr,
                                                 const float* __restrict__ dinv,
                                                 const float* __restrict__ b2,
                                                 float* __restrict__ out) {
    int i = blockIdx.x * 256 + threadIdx.x;
    if (i >= N_NODES) return;
    int beg = off[i], end = off[i + 1];
    float2 a = h2p[i];                                // self-loop term
    for (int s = beg; s < end; ++s) {
        float2 v = h2p[csr[s]];
        a.x += v.x;
        a.y += v.y;
    }
    float di = dinv[i];
    out[i * 2 + 0] = di * a.x + b2[0];
    out[i * 2 + 1] = di * a.y + b2[1];
}

extern "C" void kernel_launch(void* const* d_in, const int* in_sizes, int n_in,
                              void* d_out, int out_size, void* d_ws, size_t ws_size,
                              hipStream_t stream) {
    const float* x  = (const float*)d_in[0];
    const int*   ei = (const int*)d_in[1];
    const float* W1 = (const float*)d_in[2];
    const float* b1 = (const float*)d_in[3];
    const float* W2 = (const float*)d_in[4];
    const float* b2 = (const float*)d_in[5];
    float* out = (float*)d_out;

    const int* src = ei;
    const int* dst = ei + N_EDGES;

    // workspace layout (4 B units, offsets multiple of 256 -> 16B aligned)
    int*   wsi    = (int*)d_ws;
    int*   cnt    = wsi;                 // 100352
    int*   off    = wsi + 100352;        // 100352 (needs N+1)
    int*   cursor = wsi + 200704;        // 100352
    int*   loc    = wsi + 301056;        // 100352
    int*   bsum   = wsi + 401408;        // 512
    int*   boff   = wsi + 401920;        // 512
    int*   csr    = wsi + 402432;        // 1600000
    float* h1p    = (float*)(wsi + 2002432);   // 6400000
    float2* h2p   = (float2*)(wsi + 8402432);  // 100000 float2 = 200000
    float* dinv   = (float*)(wsi + 8602688);   // 100352

    const int NB = (N_NODES + 255) / 256;      // 391
    dim3 B(256);
    k_zero_cnt  <<<NB, B, 0, stream>>>(cnt);
    k_hist      <<<(N_EDGES + 255) / 256, B, 0, stream>>>(dst, cnt);
    k_dinv      <<<NB, B, 0, stream>>>(cnt, dinv);
    k_scan_block<<<NB, B, 0, stream>>>(cnt, loc, bsum);
    k_scan_top  <<<1, 512, 0, stream>>>(bsum, boff, NB);
    k_scan_fin  <<<NB, B, 0, stream>>>(cnt, loc, boff, off, cursor);
    k_reorder   <<<(N_EDGES + 255) / 256, B, 0, stream>>>(src, dst, cursor, csr);

    k_gemm1     <<<1024, B, 0, stream>>>(x, W1, dinv, h1p);
    k_gather1   <<<N_NODES / 4, B, 0, stream>>>(h1p, off, csr, dinv, b1, W2, h2p);
    k_gather2   <<<NB, B, 0, stream>>>(h2p, off, csr, dinv, b2, out);
}